// Round 5
// baseline (329.489 us; speedup 1.0000x reference)
//
#include <hip/hip_runtime.h>
#include <hip/hip_cooperative_groups.h>
#include <math.h>

namespace cg = cooperative_groups;

// Problem constants (from reference)
#define BB 16
#define CC 3
#define OO 32
#define HH 128
#define WW 128
#define OH 124
#define OW 124
#define NPIX (OH * OW)          // 15376
#define NG   (NPIX / 4)         // 3844 4-pixel groups
#define GW   (OW / 4)           // 31 groups per output row
#define KF 25.0f

#define OG2  4                  // o-groups in partial phase (8 o's each)
#define OPT2 8
#define OGF  4                  // o-groups in final phase (8 o's each)
#define OPTF 8

#define NBLK 1024               // 4 blocks/CU co-resident
#define TPB  256

#if defined(__has_builtin)
#if __has_builtin(__builtin_amdgcn_sqrtf)
#define FSQRT(x) __builtin_amdgcn_sqrtf(x)
#else
#define FSQRT(x) sqrtf(x)
#endif
#else
#define FSQRT(x) sqrtf(x)
#endif

// ---------------------------------------------------------------------------
// Single cooperative kernel: 4 phases separated by grid.sync().
// Phase 1: 5x5 window sums per (b,c,pix4)          — 184,512 tasks
// Phase 2: o-octet dist partials per (b,og,pix4)   — 246,016 tasks
// Phase 3: per-pixel 1/std over 64 partial rows    —  15,376 tasks
// Phase 4: output per (b,og,pix4), 8 o's, f4 store — 246,016 tasks
// ---------------------------------------------------------------------------
__global__ __launch_bounds__(TPB, 4)
void fused_all(const float* __restrict__ x,
               const float* __restrict__ wgt,
               float* __restrict__ s1,
               float* __restrict__ s2,
               float* __restrict__ psum,
               float* __restrict__ psq,
               float* __restrict__ invstd,
               float* __restrict__ out) {
    cg::grid_group grid = cg::this_grid();
    const int tid = blockIdx.x * blockDim.x + threadIdx.x;
    const int NT  = gridDim.x * blockDim.x;

    // ---------------- Phase 1: window sums ----------------
    for (int t = tid; t < BB * CC * NG; t += NT) {
        int g  = t % NG;
        int bc = t / NG;
        int i  = g / GW;
        int j0 = (g % GW) * 4;
        int pixb = i * OW + j0;

        const float* img = x + (size_t)bc * (HH * WW);
        float S1[4] = {0, 0, 0, 0}, S2[4] = {0, 0, 0, 0};
#pragma unroll
        for (int di = 0; di < 5; ++di) {
            const float4* rp = reinterpret_cast<const float4*>(img + (i + di) * WW + j0);
            float4 lo = rp[0], hi = rp[1];
            float v[8] = {lo.x, lo.y, lo.z, lo.w, hi.x, hi.y, hi.z, hi.w};
            float q[8];
#pragma unroll
            for (int k = 0; k < 8; ++k) q[k] = v[k] * v[k];
            float r  = v[0] + v[1] + v[2] + v[3] + v[4];
            float rq = q[0] + q[1] + q[2] + q[3] + q[4];
            S1[0] += r;  S2[0] += rq;
#pragma unroll
            for (int u = 1; u < 4; ++u) {
                r  += v[u + 4] - v[u - 1];
                rq += q[u + 4] - q[u - 1];
                S1[u] += r;  S2[u] += rq;
            }
        }
        float4 a  = {S1[0], S1[1], S1[2], S1[3]};
        float4 qq = {S2[0], S2[1], S2[2], S2[3]};
        *reinterpret_cast<float4*>(&s1[(size_t)bc * NPIX + pixb]) = a;
        *reinterpret_cast<float4*>(&s2[(size_t)bc * NPIX + pixb]) = qq;
    }
    grid.sync();

    // ---------------- Phase 2: o-octet partials ----------------
    for (int t = tid; t < BB * OG2 * NG; t += NT) {
        int g  = t % NG;
        int r_ = t / NG;
        int og = r_ % OG2;
        int b  = r_ / OG2;
        int i  = g / GW;
        int j0 = (g % GW) * 4;
        int pixb = i * OW + j0;

        float S1c[CC][4], S2c[CC][4];
#pragma unroll
        for (int c = 0; c < CC; ++c) {
            float4 a = *reinterpret_cast<const float4*>(&s1[(size_t)(b * CC + c) * NPIX + pixb]);
            float4 q = *reinterpret_cast<const float4*>(&s2[(size_t)(b * CC + c) * NPIX + pixb]);
            S1c[c][0] = a.x; S1c[c][1] = a.y; S1c[c][2] = a.z; S1c[c][3] = a.w;
            S2c[c][0] = q.x; S2c[c][1] = q.y; S2c[c][2] = q.z; S2c[c][3] = q.w;
        }
        float sum[4] = {0, 0, 0, 0}, sq[4] = {0, 0, 0, 0};
#pragma unroll
        for (int oo = 0; oo < OPT2; ++oo) {
            int o = og * OPT2 + oo;
            float d[4] = {0, 0, 0, 0};
#pragma unroll
            for (int c = 0; c < CC; ++c) {
                float w  = wgt[o * CC + c];
                float tw = 2.0f * w;
                float kw = KF * w * w;
#pragma unroll
                for (int u = 0; u < 4; ++u) {
                    float inner = S2c[c][u] - tw * S1c[c][u] + kw;
                    d[u] += FSQRT(fmaxf(inner, 0.0f));
                }
            }
#pragma unroll
            for (int u = 0; u < 4; ++u) { sum[u] += d[u]; sq[u] += d[u] * d[u]; }
        }
        float4 fs = {sum[0], sum[1], sum[2], sum[3]};
        float4 fq = {sq[0], sq[1], sq[2], sq[3]};
        *reinterpret_cast<float4*>(&psum[(size_t)(b * OG2 + og) * NPIX + pixb]) = fs;
        *reinterpret_cast<float4*>(&psq [(size_t)(b * OG2 + og) * NPIX + pixb]) = fq;
    }
    grid.sync();

    // ---------------- Phase 3: per-pixel 1/std ----------------
    for (int pix = tid; pix < NPIX; pix += NT) {
        double sm = 0.0, sQ = 0.0;
#pragma unroll 8
        for (int r = 0; r < BB * OG2; ++r) {
            sm += (double)psum[(size_t)r * NPIX + pix];
            sQ += (double)psq [(size_t)r * NPIX + pix];
        }
        const double n = (double)(BB * OO);
        double mean = sm / n;
        double var = (sQ - n * mean * mean) / (n - 1.0);
        if (var < 0.0) var = 0.0;
        invstd[pix] = (float)(1.0 / sqrt(var));
    }
    grid.sync();

    // ---------------- Phase 4: final output ----------------
    for (int t = tid; t < BB * OGF * NG; t += NT) {
        int g  = t % NG;
        int r_ = t / NG;
        int og = r_ % OGF;
        int b  = r_ / OGF;
        int i  = g / GW;
        int j0 = (g % GW) * 4;
        int pixb = i * OW + j0;

        float S1c[CC][4], S2c[CC][4];
#pragma unroll
        for (int c = 0; c < CC; ++c) {
            float4 a = *reinterpret_cast<const float4*>(&s1[(size_t)(b * CC + c) * NPIX + pixb]);
            float4 q = *reinterpret_cast<const float4*>(&s2[(size_t)(b * CC + c) * NPIX + pixb]);
            S1c[c][0] = a.x; S1c[c][1] = a.y; S1c[c][2] = a.z; S1c[c][3] = a.w;
            S2c[c][0] = q.x; S2c[c][1] = q.y; S2c[c][2] = q.z; S2c[c][3] = q.w;
        }
        float4 iv = *reinterpret_cast<const float4*>(&invstd[pixb]);
        float isd[4] = {iv.x, iv.y, iv.z, iv.w};

#pragma unroll
        for (int oo = 0; oo < OPTF; ++oo) {
            int o = og * OPTF + oo;
            float d[4] = {0, 0, 0, 0};
#pragma unroll
            for (int c = 0; c < CC; ++c) {
                float w  = wgt[o * CC + c];
                float tw = 2.0f * w;
                float kw = KF * w * w;
#pragma unroll
                for (int u = 0; u < 4; ++u) {
                    float inner = S2c[c][u] - tw * S1c[c][u] + kw;
                    d[u] += FSQRT(fmaxf(inner, 0.0f));
                }
            }
            float4 r;
            float z0 = d[0] * isd[0]; r.x = __expf(-0.5f * z0 * z0);
            float z1 = d[1] * isd[1]; r.y = __expf(-0.5f * z1 * z1);
            float z2 = d[2] * isd[2]; r.z = __expf(-0.5f * z2 * z2);
            float z3 = d[3] * isd[3]; r.w = __expf(-0.5f * z3 * z3);
            *reinterpret_cast<float4*>(&out[(size_t)(b * OO + o) * NPIX + pixb]) = r;
        }
    }
}

// ===========================================================================
// Fallback path (non-cooperative), identical math — used only if the
// cooperative launch is rejected. Same semantics, deterministic.
// ===========================================================================
__global__ void win_sums4(const float* __restrict__ x,
                          float* __restrict__ s1,
                          float* __restrict__ s2) {
    int idx = blockIdx.x * blockDim.x + threadIdx.x;
    if (idx >= BB * CC * NG) return;
    int g  = idx % NG;
    int bc = idx / NG;
    int i  = g / GW;
    int j0 = (g % GW) * 4;
    int pixb = i * OW + j0;
    const float* img = x + (size_t)bc * (HH * WW);
    float S1[4] = {0, 0, 0, 0}, S2[4] = {0, 0, 0, 0};
#pragma unroll
    for (int di = 0; di < 5; ++di) {
        const float4* rp = reinterpret_cast<const float4*>(img + (i + di) * WW + j0);
        float4 lo = rp[0], hi = rp[1];
        float v[8] = {lo.x, lo.y, lo.z, lo.w, hi.x, hi.y, hi.z, hi.w};
        float q[8];
#pragma unroll
        for (int k = 0; k < 8; ++k) q[k] = v[k] * v[k];
        float r  = v[0] + v[1] + v[2] + v[3] + v[4];
        float rq = q[0] + q[1] + q[2] + q[3] + q[4];
        S1[0] += r;  S2[0] += rq;
#pragma unroll
        for (int u = 1; u < 4; ++u) {
            r  += v[u + 4] - v[u - 1];
            rq += q[u + 4] - q[u - 1];
            S1[u] += r;  S2[u] += rq;
        }
    }
    float4 a  = {S1[0], S1[1], S1[2], S1[3]};
    float4 qq = {S2[0], S2[1], S2[2], S2[3]};
    *reinterpret_cast<float4*>(&s1[(size_t)bc * NPIX + pixb]) = a;
    *reinterpret_cast<float4*>(&s2[(size_t)bc * NPIX + pixb]) = qq;
}

__global__ void partial8(const float* __restrict__ s1,
                         const float* __restrict__ s2,
                         const float* __restrict__ wgt,
                         float* __restrict__ psum,
                         float* __restrict__ psq) {
    int idx = blockIdx.x * blockDim.x + threadIdx.x;
    if (idx >= BB * OG2 * NG) return;
    int g  = idx % NG;
    int r_ = idx / NG;
    int og = r_ % OG2;
    int b  = r_ / OG2;
    int i  = g / GW;
    int j0 = (g % GW) * 4;
    int pixb = i * OW + j0;
    float S1c[CC][4], S2c[CC][4];
#pragma unroll
    for (int c = 0; c < CC; ++c) {
        float4 a = *reinterpret_cast<const float4*>(&s1[(size_t)(b * CC + c) * NPIX + pixb]);
        float4 q = *reinterpret_cast<const float4*>(&s2[(size_t)(b * CC + c) * NPIX + pixb]);
        S1c[c][0] = a.x; S1c[c][1] = a.y; S1c[c][2] = a.z; S1c[c][3] = a.w;
        S2c[c][0] = q.x; S2c[c][1] = q.y; S2c[c][2] = q.z; S2c[c][3] = q.w;
    }
    float sum[4] = {0, 0, 0, 0}, sq[4] = {0, 0, 0, 0};
#pragma unroll
    for (int oo = 0; oo < OPT2; ++oo) {
        int o = og * OPT2 + oo;
        float d[4] = {0, 0, 0, 0};
#pragma unroll
        for (int c = 0; c < CC; ++c) {
            float w  = wgt[o * CC + c];
            float tw = 2.0f * w;
            float kw = KF * w * w;
#pragma unroll
            for (int u = 0; u < 4; ++u) {
                float inner = S2c[c][u] - tw * S1c[c][u] + kw;
                d[u] += FSQRT(fmaxf(inner, 0.0f));
            }
        }
#pragma unroll
        for (int u = 0; u < 4; ++u) { sum[u] += d[u]; sq[u] += d[u] * d[u]; }
    }
    float4 fs = {sum[0], sum[1], sum[2], sum[3]};
    float4 fq = {sq[0], sq[1], sq[2], sq[3]};
    *reinterpret_cast<float4*>(&psum[(size_t)(b * OG2 + og) * NPIX + pixb]) = fs;
    *reinterpret_cast<float4*>(&psq [(size_t)(b * OG2 + og) * NPIX + pixb]) = fq;
}

__global__ void inv_std_kernel(const float* __restrict__ psum,
                               const float* __restrict__ psq,
                               float* __restrict__ invstd) {
    int pix = blockIdx.x * blockDim.x + threadIdx.x;
    if (pix >= NPIX) return;
    double sm = 0.0, sQ = 0.0;
#pragma unroll 8
    for (int r = 0; r < BB * OG2; ++r) {
        sm += (double)psum[(size_t)r * NPIX + pix];
        sQ += (double)psq [(size_t)r * NPIX + pix];
    }
    const double n = (double)(BB * OO);
    double mean = sm / n;
    double var = (sQ - n * mean * mean) / (n - 1.0);
    if (var < 0.0) var = 0.0;
    invstd[pix] = (float)(1.0 / sqrt(var));
}

__global__ void final8(const float* __restrict__ s1,
                       const float* __restrict__ s2,
                       const float* __restrict__ wgt,
                       const float* __restrict__ invstd,
                       float* __restrict__ out) {
    int idx = blockIdx.x * blockDim.x + threadIdx.x;
    if (idx >= BB * OGF * NG) return;
    int g  = idx % NG;
    int r_ = idx / NG;
    int og = r_ % OGF;
    int b  = r_ / OGF;
    int i  = g / GW;
    int j0 = (g % GW) * 4;
    int pixb = i * OW + j0;
    float S1c[CC][4], S2c[CC][4];
#pragma unroll
    for (int c = 0; c < CC; ++c) {
        float4 a = *reinterpret_cast<const float4*>(&s1[(size_t)(b * CC + c) * NPIX + pixb]);
        float4 q = *reinterpret_cast<const float4*>(&s2[(size_t)(b * CC + c) * NPIX + pixb]);
        S1c[c][0] = a.x; S1c[c][1] = a.y; S1c[c][2] = a.z; S1c[c][3] = a.w;
        S2c[c][0] = q.x; S2c[c][1] = q.y; S2c[c][2] = q.z; S2c[c][3] = q.w;
    }
    float4 iv = *reinterpret_cast<const float4*>(&invstd[pixb]);
    float isd[4] = {iv.x, iv.y, iv.z, iv.w};
#pragma unroll
    for (int oo = 0; oo < OPTF; ++oo) {
        int o = og * OPTF + oo;
        float d[4] = {0, 0, 0, 0};
#pragma unroll
        for (int c = 0; c < CC; ++c) {
            float w  = wgt[o * CC + c];
            float tw = 2.0f * w;
            float kw = KF * w * w;
#pragma unroll
            for (int u = 0; u < 4; ++u) {
                float inner = S2c[c][u] - tw * S1c[c][u] + kw;
                d[u] += FSQRT(fmaxf(inner, 0.0f));
            }
        }
        float4 r;
        float z0 = d[0] * isd[0]; r.x = __expf(-0.5f * z0 * z0);
        float z1 = d[1] * isd[1]; r.y = __expf(-0.5f * z1 * z1);
        float z2 = d[2] * isd[2]; r.z = __expf(-0.5f * z2 * z2);
        float z3 = d[3] * isd[3]; r.w = __expf(-0.5f * z3 * z3);
        *reinterpret_cast<float4*>(&out[(size_t)(b * OO + o) * NPIX + pixb]) = r;
    }
}

// ---------------------------------------------------------------------------
extern "C" void kernel_launch(void* const* d_in, const int* in_sizes, int n_in,
                              void* d_out, int out_size, void* d_ws, size_t ws_size,
                              hipStream_t stream) {
    const float* x   = (const float*)d_in[0];   // (16,3,128,128)
    const float* wgt = (const float*)d_in[1];   // (32,3)
    float* out = (float*)d_out;                 // (16,32,124,124)

    // Workspace (floats): s1 [B*C*NPIX] | s2 [B*C*NPIX] |
    //                     psum [B*OG2*NPIX] | psq [B*OG2*NPIX] | invstd [NPIX]
    float* s1     = (float*)d_ws;
    float* s2     = s1 + (size_t)BB * CC * NPIX;
    float* psum   = s2 + (size_t)BB * CC * NPIX;
    float* psq    = psum + (size_t)BB * OG2 * NPIX;
    float* invstd = psq + (size_t)BB * OG2 * NPIX;

    void* args[] = {(void*)&x, (void*)&wgt, (void*)&s1, (void*)&s2,
                    (void*)&psum, (void*)&psq, (void*)&invstd, (void*)&out};
    hipError_t err = hipLaunchCooperativeKernel((const void*)fused_all,
                                                dim3(NBLK), dim3(TPB),
                                                args, 0, stream);
    if (err != hipSuccess) {
        // Fallback: 4 plain launches (same math)
        const int block = 256;
        {
            int total = BB * CC * NG;
            win_sums4<<<(total + block - 1) / block, block, 0, stream>>>(x, s1, s2);
        }
        {
            int total = BB * OG2 * NG;
            partial8<<<(total + block - 1) / block, block, 0, stream>>>(s1, s2, wgt, psum, psq);
        }
        {
            inv_std_kernel<<<(NPIX + block - 1) / block, block, 0, stream>>>(psum, psq, invstd);
        }
        {
            int total = BB * OGF * NG;
            final8<<<(total + block - 1) / block, block, 0, stream>>>(s1, s2, wgt, invstd, out);
        }
    }
}

// Round 6
// 17.920 us; speedup vs baseline: 18.3871x; 18.3871x over previous
//
#include <hip/hip_runtime.h>
#include <math.h>

// Problem constants (from reference)
#define BB 16
#define CC 3
#define OO 32
#define HH 128
#define WW 128
#define OH 124
#define OW 124
#define NPIX (OH * OW)          // 15376
#define NG   (NPIX / 4)         // 3844 4-pixel groups
#define GW   (OW / 4)           // 31 groups per output row
#define KF 25.0f

#define TPB  256
#define NBLK (NG / 4)           // 961 blocks, 4 pix4-groups (16 pixels) each

#if defined(__has_builtin)
#if __has_builtin(__builtin_amdgcn_sqrtf)
#define FSQRT(x) __builtin_amdgcn_sqrtf(x)
#else
#define FSQRT(x) sqrtf(x)
#endif
#else
#define FSQRT(x) sqrtf(x)
#endif

// ---------------------------------------------------------------------------
// ONE kernel. Block owns 16 pixels (4 pix4 groups) x all (16 b, 32 o).
// Phase 0: window sums from x -> LDS           (192 threads: 48 bc x 4 p4)
// Phase 1: dist partials, dist kept in VGPRs   (256 threads: 16b x 4og x 4p4)
// Phase 2: per-pixel unbiased 1/std in LDS     (64 + 16 threads, double)
// Phase 3: out = exp(-0.5 (dist*invstd)^2)     (256 threads, float4 stores)
// No global intermediates, no extra launches, no grid sync.
// ---------------------------------------------------------------------------
__global__ __launch_bounds__(TPB, 4)
void fused_one(const float* __restrict__ x,
               const float* __restrict__ wgt,
               float* __restrict__ out) {
    __shared__ float  sS1[BB * CC][16];   // 3 KB  window sums
    __shared__ float  sS2[BB * CC][16];   // 3 KB
    __shared__ float  sPS[BB * 4][16];    // 4 KB  per-(b,og) dist sums
    __shared__ float  sPQ[BB * 4][16];    // 4 KB  per-(b,og) dist sumsq
    __shared__ float  sW[OO * CC];        // 384 B weights
    __shared__ float  sInv[16];           // 1/std per pixel
    __shared__ double sRm[16][4];         // reduction scratch
    __shared__ double sRq[16][4];

    const int t  = threadIdx.x;
    const int g0 = blockIdx.x * 4;        // first pix4 group of this block

    // ---------------- Phase 0: weights + window sums ----------------
    if (t < OO * CC) sW[t] = wgt[t];
    if (t < BB * CC * 4) {                // 192 active
        int bc = t >> 2;                  // 0..47
        int p4 = t & 3;                   // 0..3
        int g  = g0 + p4;
        int i  = g / GW;
        int j0 = (g % GW) * 4;
        const float* img = x + (size_t)bc * (HH * WW);
        float S1[4] = {0, 0, 0, 0}, S2[4] = {0, 0, 0, 0};
#pragma unroll
        for (int di = 0; di < 5; ++di) {
            const float4* rp = reinterpret_cast<const float4*>(img + (i + di) * WW + j0);
            float4 lo = rp[0], hi = rp[1];
            float v[8] = {lo.x, lo.y, lo.z, lo.w, hi.x, hi.y, hi.z, hi.w};
            float q[8];
#pragma unroll
            for (int k = 0; k < 8; ++k) q[k] = v[k] * v[k];
            float r  = v[0] + v[1] + v[2] + v[3] + v[4];
            float rq = q[0] + q[1] + q[2] + q[3] + q[4];
            S1[0] += r;  S2[0] += rq;
#pragma unroll
            for (int u = 1; u < 4; ++u) {
                r  += v[u + 4] - v[u - 1];
                rq += q[u + 4] - q[u - 1];
                S1[u] += r;  S2[u] += rq;
            }
        }
#pragma unroll
        for (int u = 0; u < 4; ++u) {
            sS1[bc][p4 * 4 + u] = S1[u];
            sS2[bc][p4 * 4 + u] = S2[u];
        }
    }
    __syncthreads();

    // ---------------- Phase 1: dist partials (dist stays in registers) ----
    const int b  = t >> 4;        // 0..15
    const int og = (t >> 2) & 3;  // 0..3  (8 o's each)
    const int p4 = t & 3;         // 0..3  (4 pixels each)

    float S1c[CC][4], S2c[CC][4];
#pragma unroll
    for (int c = 0; c < CC; ++c) {
#pragma unroll
        for (int u = 0; u < 4; ++u) {
            S1c[c][u] = sS1[b * CC + c][p4 * 4 + u];
            S2c[c][u] = sS2[b * CC + c][p4 * 4 + u];
        }
    }

    float dist[8][4];
    float sum[4] = {0, 0, 0, 0}, sq[4] = {0, 0, 0, 0};
#pragma unroll
    for (int oo = 0; oo < 8; ++oo) {
        int o = og * 8 + oo;
        float d[4] = {0, 0, 0, 0};
#pragma unroll
        for (int c = 0; c < CC; ++c) {
            float w  = sW[o * CC + c];
            float tw = 2.0f * w;
            float kw = KF * w * w;
#pragma unroll
            for (int u = 0; u < 4; ++u) {
                float inner = S2c[c][u] - tw * S1c[c][u] + kw;
                d[u] += FSQRT(fmaxf(inner, 0.0f));
            }
        }
#pragma unroll
        for (int u = 0; u < 4; ++u) {
            dist[oo][u] = d[u];
            sum[u] += d[u];
            sq[u]  += d[u] * d[u];
        }
    }
#pragma unroll
    for (int u = 0; u < 4; ++u) {
        sPS[b * 4 + og][p4 * 4 + u] = sum[u];
        sPQ[b * 4 + og][p4 * 4 + u] = sq[u];
    }
    __syncthreads();

    // ---------------- Phase 2: per-pixel 1/std (double) ----------------
    if (t < 64) {
        int pix = t >> 2;   // 0..15
        int seg = t & 3;    // 0..3, 16 rows each
        double sm = 0.0, sQ = 0.0;
#pragma unroll
        for (int k = 0; k < 16; ++k) {
            sm += (double)sPS[seg * 16 + k][pix];
            sQ += (double)sPQ[seg * 16 + k][pix];
        }
        sRm[pix][seg] = sm;
        sRq[pix][seg] = sQ;
    }
    __syncthreads();
    if (t < 16) {
        double sm = sRm[t][0] + sRm[t][1] + sRm[t][2] + sRm[t][3];
        double sQ = sRq[t][0] + sRq[t][1] + sRq[t][2] + sRq[t][3];
        const double n = (double)(BB * OO);
        double mean = sm / n;
        double var = (sQ - n * mean * mean) / (n - 1.0);
        if (var < 0.0) var = 0.0;
        sInv[t] = (float)(1.0 / sqrt(var));
    }
    __syncthreads();

    // ---------------- Phase 3: output ----------------
    float isd[4];
#pragma unroll
    for (int u = 0; u < 4; ++u) isd[u] = sInv[p4 * 4 + u];
    const int g = g0 + p4;
    const size_t pixbase = (size_t)g * 4;   // == i*OW + j0

#pragma unroll
    for (int oo = 0; oo < 8; ++oo) {
        int o = og * 8 + oo;
        float4 r;
        float z0 = dist[oo][0] * isd[0]; r.x = __expf(-0.5f * z0 * z0);
        float z1 = dist[oo][1] * isd[1]; r.y = __expf(-0.5f * z1 * z1);
        float z2 = dist[oo][2] * isd[2]; r.z = __expf(-0.5f * z2 * z2);
        float z3 = dist[oo][3] * isd[3]; r.w = __expf(-0.5f * z3 * z3);
        *reinterpret_cast<float4*>(&out[(size_t)(b * OO + o) * NPIX + pixbase]) = r;
    }
}

// ---------------------------------------------------------------------------
extern "C" void kernel_launch(void* const* d_in, const int* in_sizes, int n_in,
                              void* d_out, int out_size, void* d_ws, size_t ws_size,
                              hipStream_t stream) {
    const float* x   = (const float*)d_in[0];   // (16,3,128,128)
    const float* wgt = (const float*)d_in[1];   // (32,3)
    float* out = (float*)d_out;                 // (16,32,124,124)

    fused_one<<<NBLK, TPB, 0, stream>>>(x, wgt, out);
}